// Round 8
// baseline (800.319 us; speedup 1.0000x reference)
//
#include <hip/hip_runtime.h>
#include <hip/hip_bf16.h>
#include <math.h>

#define NN 50000
#define EE 800000
#define RNA_D 645
#define KFUSE 651
#define KPACK 704
#define HD 128
#define GG 200
#define SAK 72    // LDS k-stride (bf16): 64+8 pad
#define HGS 136   // persistent LDS row stride (bf16) for tail buffer

typedef __attribute__((ext_vector_type(8))) short shortx8;
typedef __attribute__((ext_vector_type(4))) float floatx4;

__device__ __forceinline__ float lrelu(float x){ return x >= 0.f ? x : 0.2f*x; }
__device__ __forceinline__ short f2bf(float x){
  union { __hip_bfloat16 h; short s; } u; u.h = __float2bfloat16(x); return u.s;
}
__device__ __forceinline__ float bf2f(short s){
  union { float f; unsigned u; } c; c.u = ((unsigned)(unsigned short)s) << 16; return c.f;
}
__device__ __forceinline__ float2 upk(unsigned u){
  union { float f; unsigned v; } a, b;
  a.v = u << 16; b.v = u & 0xffff0000u;
  return make_float2(a.f, b.f);
}

// ---------------- graph prep ----------------
__global__ void hist_gstart_kernel(const int* __restrict__ dst, int* __restrict__ deg,
                                   const int* __restrict__ batch, int* __restrict__ gstart){
  int e = blockIdx.x*256 + threadIdx.x;
  if (e < EE) atomicAdd(&deg[dst[e]], 1);
  if (e < NN){
    int g = batch[e];
    if (e == 0){ for (int gg=0; gg<=g; ++gg) gstart[gg] = 0; }
    else { int gp = batch[e-1]; for (int gg=gp+1; gg<=g; ++gg) gstart[gg] = e; }
    if (e == NN-1){ for (int gg=g+1; gg<=GG; ++gg) gstart[gg] = NN; }
  }
}
// single-block scan: 1024 threads, 49 elems each
__launch_bounds__(1024)
__global__ void scan_all_kernel(const int* __restrict__ deg, int* __restrict__ row_start,
                                int* __restrict__ cursor){
  __shared__ int s[1024];
  int t = threadIdx.x;
  int b0 = t*49, b1 = min(b0+49, NN);
  int sum = 0;
  for (int i=b0;i<b1;++i) sum += deg[i];
  s[t] = sum;
  __syncthreads();
  for (int off=1; off<1024; off<<=1){
    int v = (t>=off) ? s[t-off] : 0;
    __syncthreads();
    s[t] += v;
    __syncthreads();
  }
  int pre = (t==0) ? 0 : s[t-1];
  for (int i=b0;i<b1;++i){ int d=deg[i]; row_start[i]=pre; cursor[i]=pre; pre+=d; }
  if (t==0) row_start[NN] = EE;
}
__global__ void scatter_kernel(const int* __restrict__ srcl, const int* __restrict__ dstl,
                               int* __restrict__ cursor, int* __restrict__ csr_src){
  int e = blockIdx.x*256 + threadIdx.x;
  if (e >= EE) return;
  int d = dstl[e];
  int slot = atomicAdd(&cursor[d], 1);
  csr_src[slot] = srcl[e];
}

// ---------------- weight prep ----------------
__global__ void wprep_all_kernel(const float* __restrict__ Wf, const float* __restrict__ Wg,
                                 const float* __restrict__ Wgt, const float* __restrict__ Wh,
                                 const float* __restrict__ W1,
                                 short* __restrict__ Tf, short* __restrict__ Tg,
                                 short* __restrict__ Tgt, short* __restrict__ Th,
                                 short* __restrict__ T1){
  int idx = blockIdx.x*256 + threadIdx.x;
  const int S0=128*KPACK, S1=128*128, S2=128*256, S3=128*128, S4=64*128;
  if (idx < S0){ int n=idx/KPACK, k=idx-n*KPACK; Tf[idx]=f2bf(k<KFUSE ? Wf[k*128+n] : 0.f); return; }
  idx -= S0;
  if (idx < S1){ int n=idx>>7, k=idx&127; Tg[idx]=f2bf(Wg[k*128+n]); return; }
  idx -= S1;
  if (idx < S2){ int n=idx>>8, k=idx&255; Tgt[idx]=f2bf(Wgt[k*128+n]); return; }
  idx -= S2;
  if (idx < S3){ int n=idx>>7, k=idx&127; Th[idx]=f2bf(Wh[k*128+n]); return; }
  idx -= S3;
  if (idx < S4){ int n=idx>>7, k=idx&127; T1[idx]=f2bf(W1[k*64+n]); return; }
}

// ---------------- fuse GEMM: direct rna/ss read, +bias LN(128) relu -> hb (bf16) ----
__launch_bounds__(256)
__global__ void fuse_gemm_kernel(const float* __restrict__ rna, const float* __restrict__ ss,
                                 const short* __restrict__ Wt, const float* __restrict__ bias,
                                 const float* __restrict__ gw, const float* __restrict__ gb,
                                 short* __restrict__ hb){
  __shared__ short sA[128*SAK];
  __shared__ short sB[128*SAK];
  const int tid  = threadIdx.x;
  const int wave = tid >> 6, lane = tid & 63;
  const int quad = lane >> 4, l16 = lane & 15;
  const int rowBase = blockIdx.x * 128;

  floatx4 acc[2][8];
  #pragma unroll
  for (int t=0;t<2;++t)
    #pragma unroll
    for (int ct=0;ct<8;++ct)
      #pragma unroll
      for (int j=0;j<4;++j) acc[t][ct][j] = 0.f;

  const int rsub = tid >> 6;     // 0..3
  const int col  = tid & 63;

  for (int k0 = 0; k0 < KPACK; k0 += 64){
    // stage A: lane-per-column, coalesced dword loads from odd-stride rna
    #pragma unroll
    for (int i=0;i<32;++i){
      int row = i*4 + rsub;
      int gr = rowBase + row;
      int gk = k0 + col;
      float v = 0.f;
      if (gr < NN && gk < KFUSE)
        v = (gk < RNA_D) ? rna[(size_t)gr*RNA_D + gk] : ss[gr*6 + (gk - RNA_D)];
      sA[row*SAK + col] = f2bf(v);
    }
    // stage B
    {
      int bcol = tid >> 1, kb = k0 + (tid&1)*32;
      #pragma unroll
      for (int q8=0;q8<4;++q8)
        *(shortx8*)&sB[bcol*SAK + (tid&1)*32 + q8*8] = *(const shortx8*)&Wt[(size_t)bcol*KPACK + kb + q8*8];
    }
    __syncthreads();
    #pragma unroll
    for (int ks=0; ks<2; ++ks){
      int kb = ks*32 + quad*8;
      shortx8 af0 = *(const shortx8*)&sA[(wave*32 +      l16)*SAK + kb];
      shortx8 af1 = *(const shortx8*)&sA[(wave*32 + 16 + l16)*SAK + kb];
      #pragma unroll
      for (int ct=0; ct<8; ++ct){
        shortx8 bf = *(const shortx8*)&sB[(ct*16 + l16)*SAK + kb];
        acc[0][ct] = __builtin_amdgcn_mfma_f32_16x16x32_bf16(af0, bf, acc[0][ct], 0,0,0);
        acc[1][ct] = __builtin_amdgcn_mfma_f32_16x16x32_bf16(af1, bf, acc[1][ct], 0,0,0);
      }
    }
    __syncthreads();
  }
  // epilogue: +bias, LN(128), relu -> bf16
  float biasv[8], gv[8], bv[8];
  #pragma unroll
  for (int ct=0;ct<8;++ct){
    biasv[ct] = bias[ct*16+l16]; gv[ct] = gw[ct*16+l16]; bv[ct] = gb[ct*16+l16];
  }
  #pragma unroll
  for (int t=0;t<2;++t)
    #pragma unroll
    for (int i=0;i<4;++i){
      int gr = rowBase + wave*32 + t*16 + quad*4 + i;
      float v[8]; float s=0.f, q=0.f;
      #pragma unroll
      for (int ct=0;ct<8;++ct){
        v[ct] = acc[t][ct][i] + biasv[ct];
        s += v[ct]; q = fmaf(v[ct], v[ct], q);
      }
      #pragma unroll
      for (int off=1; off<16; off<<=1){ s += __shfl_xor(s,off); q += __shfl_xor(q,off); }
      float mean = s * (1.f/128.f);
      float inv  = rsqrtf(q*(1.f/128.f) - mean*mean + 1e-5f);
      if (gr < NN){
        #pragma unroll
        for (int ct=0;ct<8;++ct)
          hb[(size_t)gr*HD + ct*16 + l16] = f2bf(fmaxf((v[ct]-mean)*inv*gv[ct] + bv[ct], 0.f));
      }
    }
}

// ---------------- xw GEMM: K=128 -> xwb bf16 + es/ed ----
// GNA=false: A = bf16 (hb). GNA=true: A = y fp32 + graphnorm, side-writes h1b bf16.
template<bool GNA>
__launch_bounds__(256)
__global__ void xw_gemm_kernel(const short* __restrict__ Ab, const float* __restrict__ Af,
                               const short* __restrict__ Wt,
                               const float* __restrict__ as_, const float* __restrict__ ad_,
                               const int* __restrict__ batch, const float* __restrict__ gnsh,
                               const float* __restrict__ gnsc, const float* __restrict__ gnb,
                               short* __restrict__ sideb,
                               short* __restrict__ xwb, float* __restrict__ es, float* __restrict__ ed){
  __shared__ short sA[128*SAK];
  __shared__ short sB[128*SAK];
  const int tid  = threadIdx.x;
  const int wave = tid >> 6, lane = tid & 63;
  const int quad = lane >> 4, l16 = lane & 15;
  const int rowBase = blockIdx.x * 128;

  floatx4 acc[2][8];
  #pragma unroll
  for (int t=0;t<2;++t)
    #pragma unroll
    for (int ct=0;ct<8;++ct)
      #pragma unroll
      for (int j=0;j<4;++j) acc[t][ct][j] = 0.f;

  const int srow = tid >> 1, shalf = tid & 1;
  const int sgr = rowBase + srow;

  for (int k0 = 0; k0 < HD; k0 += 64){
    int kb = k0 + shalf*32;
    if (GNA){
      short tmp[32];
      int g = (sgr < NN) ? batch[sgr] : 0;
      const float* py  = Af + (size_t)sgr*HD + kb;
      const float* psh = gnsh + g*HD + kb;
      const float* psc = gnsc + g*HD + kb;
      const float* pbb = gnb + kb;
      #pragma unroll
      for (int q4=0;q4<8;++q4){
        float4 yv = (sgr < NN) ? *(const float4*)(py + q4*4) : make_float4(0.f,0.f,0.f,0.f);
        float4 sh = *(const float4*)(psh + q4*4);
        float4 sc = *(const float4*)(psc + q4*4);
        float4 bb = *(const float4*)(pbb + q4*4);
        float4 v;
        v.x = fmaxf((yv.x - sh.x)*sc.x + bb.x, 0.f);
        v.y = fmaxf((yv.y - sh.y)*sc.y + bb.y, 0.f);
        v.z = fmaxf((yv.z - sh.z)*sc.z + bb.z, 0.f);
        v.w = fmaxf((yv.w - sh.w)*sc.w + bb.w, 0.f);
        tmp[q4*4+0]=f2bf(v.x); tmp[q4*4+1]=f2bf(v.y);
        tmp[q4*4+2]=f2bf(v.z); tmp[q4*4+3]=f2bf(v.w);
      }
      #pragma unroll
      for (int q8=0;q8<4;++q8){
        shortx8 t8 = *(shortx8*)&tmp[q8*8];
        *(shortx8*)&sA[srow*SAK + shalf*32 + q8*8] = t8;
        if (sgr < NN) *(shortx8*)&sideb[(size_t)sgr*HD + kb + q8*8] = t8;
      }
    } else {
      #pragma unroll
      for (int q8=0;q8<4;++q8){
        shortx8 v = {0,0,0,0,0,0,0,0};
        if (sgr < NN) v = *(const shortx8*)&Ab[(size_t)sgr*HD + kb + q8*8];
        *(shortx8*)&sA[srow*SAK + shalf*32 + q8*8] = v;
      }
    }
    {
      int col = tid >> 1, kb2 = k0 + (tid&1)*32;
      #pragma unroll
      for (int q8=0;q8<4;++q8)
        *(shortx8*)&sB[col*SAK + (tid&1)*32 + q8*8] = *(const shortx8*)&Wt[(size_t)col*HD + kb2 + q8*8];
    }
    __syncthreads();
    #pragma unroll
    for (int ks=0; ks<2; ++ks){
      int kk = ks*32 + quad*8;
      shortx8 af0 = *(const shortx8*)&sA[(wave*32 +      l16)*SAK + kk];
      shortx8 af1 = *(const shortx8*)&sA[(wave*32 + 16 + l16)*SAK + kk];
      #pragma unroll
      for (int ct=0; ct<8; ++ct){
        shortx8 bf = *(const shortx8*)&sB[(ct*16 + l16)*SAK + kk];
        acc[0][ct] = __builtin_amdgcn_mfma_f32_16x16x32_bf16(af0, bf, acc[0][ct], 0,0,0);
        acc[1][ct] = __builtin_amdgcn_mfma_f32_16x16x32_bf16(af1, bf, acc[1][ct], 0,0,0);
      }
    }
    __syncthreads();
  }
  // epilogue: xwb bf16 + es/ed
  float asv[8], adv[8];
  #pragma unroll
  for (int ct=0;ct<8;++ct){ asv[ct] = as_[ct*16+l16]; adv[ct] = ad_[ct*16+l16]; }
  #pragma unroll
  for (int t=0;t<2;++t)
    #pragma unroll
    for (int i=0;i<4;++i){
      int gr = rowBase + wave*32 + t*16 + quad*4 + i;
      float s=0.f, d=0.f;
      #pragma unroll
      for (int ct=0;ct<8;++ct){
        float v = acc[t][ct][i];
        s = fmaf(v, asv[ct], s); d = fmaf(v, adv[ct], d);
        if (gr < NN) xwb[(size_t)gr*HD + ct*16 + l16] = f2bf(v);
      }
      #pragma unroll
      for (int off=1; off<16; off<<=1){ s += __shfl_xor(s,off); d += __shfl_xor(d,off); }
      if (l16 == 0 && gr < NN){ es[gr] = s; ed[gr] = d; }
    }
}

// ---------------- GAT aggregation: bf16 gather, padded 8-groups ----------------
__launch_bounds__(256)
__global__ void gat_aggregate_kernel(const short* __restrict__ xwb, const float* __restrict__ es,
                                     const float* __restrict__ ed, const int* __restrict__ row_start,
                                     const int* __restrict__ csr_src, const float* __restrict__ bgat,
                                     float* __restrict__ out){
  int gid = blockIdx.x*256 + threadIdx.x;
  int n = gid >> 6, lane = gid & 63;
  if (n >= NN) return;
  int beg = row_start[n], end = row_start[n+1];
  float edn = ed[n];
  float sc_self = lrelu(es[n] + edn);

  int i0 = beg + lane;
  bool v0 = i0 < end;
  int sA = v0 ? csr_src[i0] : 0;
  float eA = v0 ? lrelu(es[sA] + edn) : -3.0e38f;
  float m = fmaxf(sc_self, eA);
  for (int i = beg + 64 + lane; i < end; i += 64)
    m = fmaxf(m, lrelu(es[csr_src[i]] + edn));
  #pragma unroll
  for (int off=1; off<64; off<<=1) m = fmaxf(m, __shfl_xor(m, off));

  float wA = v0 ? __expf(eA - m) : 0.f;
  float wsum_l = wA;
  float wself = __expf(sc_self - m);
  float2 self2 = upk(*(const unsigned*)&xwb[(size_t)n*HD + 2*lane]);
  float a0 = wself*self2.x, a1 = wself*self2.y;

  int deg0 = min(end - beg, 64);
  for (int j = 0; j < deg0; j += 8){           // padded: lanes beyond deg0 have wA=0, sA=0
    int ss[8]; float ww[8]; unsigned xv[8];
    #pragma unroll
    for (int u=0;u<8;++u){ ss[u]=__shfl(sA,j+u); ww[u]=__shfl(wA,j+u); }
    #pragma unroll
    for (int u=0;u<8;++u) xv[u] = *(const unsigned*)&xwb[(size_t)ss[u]*HD + 2*lane];
    #pragma unroll
    for (int u=0;u<8;++u){ float2 f=upk(xv[u]); a0=fmaf(ww[u],f.x,a0); a1=fmaf(ww[u],f.y,a1); }
  }
  for (int c = beg + 64; c < end; c += 64){
    int i = c + lane;
    bool vb = i < end;
    int sB = vb ? csr_src[i] : 0;
    float wB = vb ? __expf(lrelu(es[sB] + edn) - m) : 0.f;
    wsum_l += wB;
    int degc = min(end - c, 64);
    for (int jj=0; jj<degc; jj+=8){
      int ss[8]; float ww[8]; unsigned xv[8];
      #pragma unroll
      for (int u=0;u<8;++u){ ss[u]=__shfl(sB,jj+u); ww[u]=__shfl(wB,jj+u); }
      #pragma unroll
      for (int u=0;u<8;++u) xv[u] = *(const unsigned*)&xwb[(size_t)ss[u]*HD + 2*lane];
      #pragma unroll
      for (int u=0;u<8;++u){ float2 f=upk(xv[u]); a0=fmaf(ww[u],f.x,a0); a1=fmaf(ww[u],f.y,a1); }
    }
  }
  #pragma unroll
  for (int off=1; off<64; off<<=1) wsum_l += __shfl_xor(wsum_l, off);
  float dinv = 1.f/(wsum_l + wself + 1e-16f);
  float2 b2 = *(const float2*)&bgat[2*lane];
  float2 o; o.x = a0*dinv + b2.x; o.y = a1*dinv + b2.y;
  *(float2*)&out[(size_t)n*HD + 2*lane] = o;
}

// ---------------- GraphNorm group stats ----------------
__launch_bounds__(256)
__global__ void gn_group_kernel(const float* __restrict__ x, const int* __restrict__ gstart,
                                const float* __restrict__ gnw, const float* __restrict__ gnms,
                                float* __restrict__ shiftv, float* __restrict__ scalev){
  int g = blockIdx.x;
  int n0 = gstart[g], n1 = gstart[g+1];
  int f = threadIdx.x & 127, half = threadIdx.x >> 7;
  float s = 0.f, q = 0.f;
  for (int n = n0 + half; n < n1; n += 2){
    float v = x[(size_t)n*HD + f];
    s += v; q = fmaf(v, v, q);
  }
  __shared__ float rs[256], rq[256];
  rs[threadIdx.x] = s; rq[threadIdx.x] = q;
  __syncthreads();
  if (threadIdx.x < 128){
    s = rs[threadIdx.x] + rs[threadIdx.x+128];
    q = rq[threadIdx.x] + rq[threadIdx.x+128];
    float c = fmaxf((float)(n1 - n0), 1.f);
    float mean = s / c;
    float ms = gnms[f];
    float var = q/c - mean*mean*ms*(2.f - ms);
    shiftv[g*HD+f] = ms*mean;
    scalev[g*HD+f] = gnw[f] / sqrtf(var + 1e-5f);
  }
}

// ---------------- tail: gate + head(+LN2) + fc1(+LN3) + fc2 ----------------
__launch_bounds__(256)
__global__ void tail_kernel(const short* __restrict__ h1b, const float* __restrict__ y2,
                            const short* __restrict__ hb, const int* __restrict__ batch,
                            const float* __restrict__ gnsh, const float* __restrict__ gnsc,
                            const float* __restrict__ gnb,
                            const short* __restrict__ Wt_gate, const float* __restrict__ b_gate,
                            const short* __restrict__ Wt_head, const float* __restrict__ b_head,
                            const float* __restrict__ ln2g, const float* __restrict__ ln2b,
                            const short* __restrict__ Wt_fc1, const float* __restrict__ b_fc1,
                            const float* __restrict__ ln3g, const float* __restrict__ ln3b,
                            const float* __restrict__ W_fc2, const float* __restrict__ b_fc2,
                            float* __restrict__ outp){
  __shared__ short hgL[128*HGS];   // persistent: h2 -> hg -> t1
  __shared__ short sA[128*SAK];
  __shared__ short sB[128*SAK];
  const int tid = threadIdx.x, wave = tid>>6, lane = tid&63;
  const int quad = lane>>4, l16 = lane&15;
  const int rowBase = blockIdx.x*128;
  const int srow = tid>>1, shalf = tid&1;
  const int sgr = rowBase + srow;

  // ===== stage 1: gate GEMM, K=256 (A = [h1 | h2=gn(y2)+h]) =====
  floatx4 acc[2][8];
  #pragma unroll
  for (int t=0;t<2;++t)
    #pragma unroll
    for (int ct=0;ct<8;++ct)
      #pragma unroll
      for (int j=0;j<4;++j) acc[t][ct][j]=0.f;

  for (int c2=0; c2<4; ++c2){
    int kb = c2*64 + shalf*32;
    if (kb < 128){
      #pragma unroll
      for (int q8=0;q8<4;++q8){
        shortx8 v = {0,0,0,0,0,0,0,0};
        if (sgr < NN) v = *(const shortx8*)&h1b[(size_t)sgr*HD + kb + q8*8];
        *(shortx8*)&sA[srow*SAK + shalf*32 + q8*8] = v;
      }
    } else {
      int cb = kb - 128;
      short tmp[32];
      int g = (sgr < NN) ? batch[sgr] : 0;
      const float* py  = y2 + (size_t)sgr*HD + cb;
      const short* ph  = hb + (size_t)sgr*HD + cb;
      const float* psh = gnsh + g*HD + cb;
      const float* psc = gnsc + g*HD + cb;
      const float* pbb = gnb + cb;
      #pragma unroll
      for (int q8=0;q8<4;++q8){
        shortx8 hv8 = {0,0,0,0,0,0,0,0};
        if (sgr < NN) hv8 = *(const shortx8*)(ph + q8*8);
        #pragma unroll
        for (int q4=0;q4<2;++q4){
          int o4 = q8*8 + q4*4;
          float4 yv = (sgr < NN) ? *(const float4*)(py + o4) : make_float4(0.f,0.f,0.f,0.f);
          float4 sh = *(const float4*)(psh + o4);
          float4 sc = *(const float4*)(psc + o4);
          float4 bb = *(const float4*)(pbb + o4);
          tmp[o4+0] = f2bf(fmaxf((yv.x - sh.x)*sc.x + bb.x, 0.f) + bf2f(hv8[q4*4+0]));
          tmp[o4+1] = f2bf(fmaxf((yv.y - sh.y)*sc.y + bb.y, 0.f) + bf2f(hv8[q4*4+1]));
          tmp[o4+2] = f2bf(fmaxf((yv.z - sh.z)*sc.z + bb.z, 0.f) + bf2f(hv8[q4*4+2]));
          tmp[o4+3] = f2bf(fmaxf((yv.w - sh.w)*sc.w + bb.w, 0.f) + bf2f(hv8[q4*4+3]));
        }
      }
      #pragma unroll
      for (int q8=0;q8<4;++q8){
        shortx8 t8 = *(shortx8*)&tmp[q8*8];
        hgL[srow*HGS/8*0] = hgL[0]; // no-op guard removed by compiler
        *(shortx8*)&hgL[srow*HGS + cb + q8*8] = t8;
        *(shortx8*)&sA[srow*SAK + shalf*32 + q8*8] = t8;
      }
    }
    {
      int col = tid >> 1, kb2 = c2*64 + (tid&1)*32;
      #pragma unroll
      for (int q8=0;q8<4;++q8)
        *(shortx8*)&sB[col*SAK + (tid&1)*32 + q8*8] = *(const shortx8*)&Wt_gate[(size_t)col*256 + kb2 + q8*8];
    }
    __syncthreads();
    #pragma unroll
    for (int ks=0; ks<2; ++ks){
      int kk = ks*32 + quad*8;
      shortx8 af0 = *(const shortx8*)&sA[(wave*32 +      l16)*SAK + kk];
      shortx8 af1 = *(const shortx8*)&sA[(wave*32 + 16 + l16)*SAK + kk];
      #pragma unroll
      for (int ct=0; ct<8; ++ct){
        shortx8 bf = *(const shortx8*)&sB[(ct*16 + l16)*SAK + kk];
        acc[0][ct] = __builtin_amdgcn_mfma_f32_16x16x32_bf16(af0, bf, acc[0][ct], 0,0,0);
        acc[1][ct] = __builtin_amdgcn_mfma_f32_16x16x32_bf16(af1, bf, acc[1][ct], 0,0,0);
      }
    }
    __syncthreads();
  }
  // gate epilogue: hg = g*h1 + (1-g)*h2 -> hgL
  {
    float biasv[8];
    #pragma unroll
    for (int ct=0;ct<8;++ct) biasv[ct] = b_gate[ct*16+l16];
    #pragma unroll
    for (int t=0;t<2;++t)
      #pragma unroll
      for (int i=0;i<4;++i){
        int row = wave*32 + t*16 + quad*4 + i;
        int gr = rowBase + row;
        #pragma unroll
        for (int ct=0;ct<8;++ct){
          int c = ct*16 + l16;
          float g = 1.f/(1.f + __expf(-(acc[t][ct][i] + biasv[ct])));
          float x1 = (gr < NN) ? bf2f(h1b[(size_t)gr*HD + c]) : 0.f;
          float x2 = bf2f(hgL[row*HGS + c]);
          hgL[row*HGS + c] = f2bf(g*x1 + (1.f-g)*x2);
        }
      }
  }
  __syncthreads();

  // ===== stage 2: head GEMM K=128, LN(128) relu -> hgL =====
  floatx4 acc2[2][8];
  #pragma unroll
  for (int t=0;t<2;++t)
    #pragma unroll
    for (int ct=0;ct<8;++ct)
      #pragma unroll
      for (int j=0;j<4;++j) acc2[t][ct][j]=0.f;
  for (int c2=0;c2<2;++c2){
    {
      int col = tid >> 1, kb2 = c2*64 + (tid&1)*32;
      #pragma unroll
      for (int q8=0;q8<4;++q8)
        *(shortx8*)&sB[col*SAK + (tid&1)*32 + q8*8] = *(const shortx8*)&Wt_head[(size_t)col*128 + kb2 + q8*8];
    }
    __syncthreads();
    #pragma unroll
    for (int ks=0; ks<2; ++ks){
      int kg = c2*64 + ks*32 + quad*8;
      int kk = ks*32 + quad*8;
      shortx8 af0 = *(const shortx8*)&hgL[(wave*32 +      l16)*HGS + kg];
      shortx8 af1 = *(const shortx8*)&hgL[(wave*32 + 16 + l16)*HGS + kg];
      #pragma unroll
      for (int ct=0; ct<8; ++ct){
        shortx8 bf = *(const shortx8*)&sB[(ct*16 + l16)*SAK + kk];
        acc2[0][ct] = __builtin_amdgcn_mfma_f32_16x16x32_bf16(af0, bf, acc2[0][ct], 0,0,0);
        acc2[1][ct] = __builtin_amdgcn_mfma_f32_16x16x32_bf16(af1, bf, acc2[1][ct], 0,0,0);
      }
    }
    __syncthreads();
  }
  {
    float biasv[8], gv[8], bv[8];
    #pragma unroll
    for (int ct=0;ct<8;++ct){
      biasv[ct] = b_head[ct*16+l16]; gv[ct] = ln2g[ct*16+l16]; bv[ct] = ln2b[ct*16+l16];
    }
    #pragma unroll
    for (int t=0;t<2;++t)
      #pragma unroll
      for (int i=0;i<4;++i){
        int row = wave*32 + t*16 + quad*4 + i;
        float v[8]; float s=0.f, q=0.f;
        #pragma unroll
        for (int ct=0;ct<8;++ct){
          v[ct] = acc2[t][ct][i] + biasv[ct];
          s += v[ct]; q = fmaf(v[ct], v[ct], q);
        }
        #pragma unroll
        for (int off=1; off<16; off<<=1){ s += __shfl_xor(s,off); q += __shfl_xor(q,off); }
        float mean = s * (1.f/128.f);
        float inv  = rsqrtf(q*(1.f/128.f) - mean*mean + 1e-5f);
        #pragma unroll
        for (int ct=0;ct<8;++ct)
          hgL[row*HGS + ct*16 + l16] = f2bf(fmaxf((v[ct]-mean)*inv*gv[ct] + bv[ct], 0.f));
      }
  }
  __syncthreads();

  // ===== stage 3: fc1 K=128 -> 64 cols, LN(64), relu, dot W_fc2 -> outp =====
  floatx4 acc3[2][4];
  #pragma unroll
  for (int t=0;t<2;++t)
    #pragma unroll
    for (int ct=0;ct<4;++ct)
      #pragma unroll
      for (int j=0;j<4;++j) acc3[t][ct][j]=0.f;
  for (int c2=0;c2<2;++c2){
    if (tid < 128){
      int col = tid >> 1, kb2 = c2*64 + (tid&1)*32;
      #pragma unroll
      for (int q8=0;q8<4;++q8)
        *(shortx8*)&sB[col*SAK + (tid&1)*32 + q8*8] = *(const shortx8*)&Wt_fc1[(size_t)col*128 + kb2 + q8*8];
    }
    __syncthreads();
    #pragma unroll
    for (int ks=0; ks<2; ++ks){
      int kg = c2*64 + ks*32 + quad*8;
      int kk = ks*32 + quad*8;
      shortx8 af0 = *(const shortx8*)&hgL[(wave*32 +      l16)*HGS + kg];
      shortx8 af1 = *(const shortx8*)&hgL[(wave*32 + 16 + l16)*HGS + kg];
      #pragma unroll
      for (int ct=0; ct<4; ++ct){
        shortx8 bf = *(const shortx8*)&sB[(ct*16 + l16)*SAK + kk];
        acc3[0][ct] = __builtin_amdgcn_mfma_f32_16x16x32_bf16(af0, bf, acc3[0][ct], 0,0,0);
        acc3[1][ct] = __builtin_amdgcn_mfma_f32_16x16x32_bf16(af1, bf, acc3[1][ct], 0,0,0);
      }
    }
    __syncthreads();
  }
  {
    float biasv[4], gv[4], bv[4], w2v[4];
    #pragma unroll
    for (int ct=0;ct<4;++ct){
      biasv[ct] = b_fc1[ct*16+l16]; gv[ct] = ln3g[ct*16+l16]; bv[ct] = ln3b[ct*16+l16];
      w2v[ct] = W_fc2[ct*16+l16];
    }
    float b2 = b_fc2[0];
    #pragma unroll
    for (int t=0;t<2;++t)
      #pragma unroll
      for (int i=0;i<4;++i){
        int gr = rowBase + wave*32 + t*16 + quad*4 + i;
        float v[4]; float s=0.f, q=0.f;
        #pragma unroll
        for (int ct=0;ct<4;++ct){
          v[ct] = acc3[t][ct][i] + biasv[ct];
          s += v[ct]; q = fmaf(v[ct], v[ct], q);
        }
        #pragma unroll
        for (int off=1; off<16; off<<=1){ s += __shfl_xor(s,off); q += __shfl_xor(q,off); }
        float mean = s * (1.f/64.f);
        float inv  = rsqrtf(q*(1.f/64.f) - mean*mean + 1e-5f);
        float p = 0.f;
        #pragma unroll
        for (int ct=0;ct<4;++ct){
          float o = fmaxf((v[ct]-mean)*inv*gv[ct] + bv[ct], 0.f);
          p = fmaf(o, w2v[ct], p);
        }
        #pragma unroll
        for (int off=1; off<16; off<<=1) p += __shfl_xor(p, off);
        if (l16 == 0 && gr < NN) outp[gr] = p + b2;
      }
  }
}

// ---------------- launch ----------------
extern "C" void kernel_launch(void* const* d_in, const int* in_sizes, int n_in,
                              void* d_out, int out_size, void* d_ws, size_t ws_size,
                              hipStream_t stream){
  const float* rna    = (const float*)d_in[0];
  const float* ss     = (const float*)d_in[1];
  const int*   eidx   = (const int*)d_in[2];
  const int*   batch  = (const int*)d_in[3];
  const float* W_fuse = (const float*)d_in[4];
  const float* b_fuse = (const float*)d_in[5];
  const float* ln1_g  = (const float*)d_in[6];
  const float* ln1_b  = (const float*)d_in[7];
  const float* W_gat  = (const float*)d_in[8];
  const float* att_src= (const float*)d_in[9];
  const float* att_dst= (const float*)d_in[10];
  const float* b_gat  = (const float*)d_in[11];
  const float* gn_w   = (const float*)d_in[12];
  const float* gn_b   = (const float*)d_in[13];
  const float* gn_ms  = (const float*)d_in[14];
  const float* W_gate = (const float*)d_in[15];
  const float* b_gate = (const float*)d_in[16];
  const float* W_head = (const float*)d_in[17];
  const float* b_head = (const float*)d_in[18];
  const float* ln2_g  = (const float*)d_in[19];
  const float* ln2_b  = (const float*)d_in[20];
  const float* W_fc1  = (const float*)d_in[21];
  const float* b_fc1  = (const float*)d_in[22];
  const float* ln3_g  = (const float*)d_in[23];
  const float* ln3_b  = (const float*)d_in[24];
  const float* W_fc2  = (const float*)d_in[25];
  const float* b_fc2  = (const float*)d_in[26];
  float* outp = (float*)d_out;

  const int* srcl = eidx;
  const int* dstl = eidx + EE;

  char* base = (char*)d_ws;
  size_t off = 0;
  auto alloc = [&](size_t bytes)->void*{
    void* p = base + off; off = (off + bytes + 255) & ~(size_t)255; return p;
  };
  short* hb   = (short*)alloc((size_t)NN*HD*2);
  short* h1b  = (short*)alloc((size_t)NN*HD*2);
  float* y    = (float*)alloc((size_t)NN*HD*4);
  short* xwb  = (short*)alloc((size_t)NN*HD*2);
  float* es   = (float*)alloc((size_t)NN*4);
  float* ed   = (float*)alloc((size_t)NN*4);
  float* shiftv = (float*)alloc(GG*HD*4);
  float* scalev = (float*)alloc(GG*HD*4);
  int* deg       = (int*)alloc((size_t)NN*4);
  int* row_start = (int*)alloc((size_t)(NN+1)*4);
  int* cursor    = (int*)alloc((size_t)NN*4);
  int* csr_src   = (int*)alloc((size_t)EE*4);
  int* gstart    = (int*)alloc((GG+1)*4);
  short* Wt_fuse = (short*)alloc((size_t)128*KPACK*2);
  short* Wt_gat  = (short*)alloc((size_t)128*128*2);
  short* Wt_gate = (short*)alloc((size_t)128*256*2);
  short* Wt_head = (short*)alloc((size_t)128*128*2);
  short* Wt_fc1  = (short*)alloc((size_t)64*128*2);

  const int GB  = (NN + 127)/128;
  const int EB  = (EE + 255)/256;
  const int WVB = (NN*64 + 255)/256;
  const int WPREP_TOT = 128*KPACK + 128*128 + 128*256 + 128*128 + 64*128;

  wprep_all_kernel<<<(WPREP_TOT+255)/256, 256, 0, stream>>>(
      W_fuse, W_gat, W_gate, W_head, W_fc1,
      Wt_fuse, Wt_gat, Wt_gate, Wt_head, Wt_fc1);

  hipMemsetAsync(deg, 0, (size_t)NN*4, stream);
  hist_gstart_kernel<<<EB, 256, 0, stream>>>(dstl, deg, batch, gstart);
  scan_all_kernel<<<1, 1024, 0, stream>>>(deg, row_start, cursor);
  scatter_kernel<<<EB, 256, 0, stream>>>(srcl, dstl, cursor, csr_src);

  // fuse + LN1 + relu -> hb (bf16), direct rna/ss read
  fuse_gemm_kernel<<<GB, 256, 0, stream>>>(rna, ss, Wt_fuse, b_fuse, ln1_g, ln1_b, hb);

  // ---- GAT layer 1 ----
  xw_gemm_kernel<false><<<GB, 256, 0, stream>>>(hb, nullptr, Wt_gat, att_src, att_dst,
      nullptr, nullptr, nullptr, nullptr, nullptr, xwb, es, ed);
  gat_aggregate_kernel<<<WVB, 256, 0, stream>>>(xwb, es, ed, row_start, csr_src, b_gat, y);
  gn_group_kernel<<<GG, 256, 0, stream>>>(y, gstart, gn_w, gn_ms, shiftv, scalev);

  // ---- GAT layer 2 (graphnorm fused into staging, side-writes h1b) ----
  xw_gemm_kernel<true><<<GB, 256, 0, stream>>>(nullptr, y, Wt_gat, att_src, att_dst,
      batch, shiftv, scalev, gn_b, h1b, xwb, es, ed);
  gat_aggregate_kernel<<<WVB, 256, 0, stream>>>(xwb, es, ed, row_start, csr_src, b_gat, y);
  gn_group_kernel<<<GG, 256, 0, stream>>>(y, gstart, gn_w, gn_ms, shiftv, scalev);

  // ---- tail: gate + head + fc1 + fc2 -> out ----
  tail_kernel<<<GB, 256, 0, stream>>>(h1b, y, hb, batch, shiftv, scalev, gn_b,
      Wt_gate, b_gate, Wt_head, b_head, ln2_g, ln2_b,
      Wt_fc1, b_fc1, ln3_g, ln3_b, W_fc2, b_fc2, outp);
}